// Round 1
// baseline (26.818 us; speedup 1.0000x reference)
//
#include <hip/hip_runtime.h>

// FSNeuronDecoupled: per-element spiking scan over T=8 steps.
//   v0 = x;  for t in 0..7:  s_t = (v - theta_t > 0);  v -= h_t * s_t
//   y = sum_t d_t * s_t
// with theta_t = theta[grain(t)]^-(t+1), etc.  GRAIN = [0,0,0,0,1,1,1,1].
// Memory-bound elementwise op: 4B read + 4B write per element.

#define T_STEPS 8

__global__ __launch_bounds__(256) void fsneuron_kernel(
    const float4* __restrict__ x4,
    const float* __restrict__ d,
    const float* __restrict__ h,
    const float* __restrict__ theta,
    float4* __restrict__ y4,
    int n4,
    const float* __restrict__ x_tail,   // scalar view for remainder
    float* __restrict__ y_tail,
    int n_total)
{
    // ---- per-thread coefficient computation (6 scalar loads, L2 broadcast) ----
    // theta_t = theta[g]^-(t+1) * TAU (TAU==1). Running reciprocal products:
    // for the provided inputs (2.0) these are exact powers of two, matching np.
    const float it0 = 1.0f / theta[0], it1 = 1.0f / theta[1];
    const float ih0 = 1.0f / h[0],     ih1 = 1.0f / h[1];
    const float id0 = 1.0f / d[0],     id1 = 1.0f / d[1];

    float th[T_STEPS], hh[T_STEPS], dd[T_STEPS];
    float pt0 = 1.0f, pt1 = 1.0f, ph0 = 1.0f, ph1 = 1.0f, pd0 = 1.0f, pd1 = 1.0f;
#pragma unroll
    for (int t = 0; t < T_STEPS; ++t) {
        pt0 *= it0; pt1 *= it1;
        ph0 *= ih0; ph1 *= ih1;
        pd0 *= id0; pd1 *= id1;
        const bool g1 = (t >= 4);           // GRAIN = [0,0,0,0,1,1,1,1]
        th[t] = g1 ? pt1 : pt0;
        hh[t] = g1 ? ph1 : ph0;
        dd[t] = g1 ? pd1 : pd0;
    }

    const int stride = gridDim.x * blockDim.x;

    // ---- main vectorized grid-stride loop ----
    for (int i = blockIdx.x * blockDim.x + threadIdx.x; i < n4; i += stride) {
        float4 v = x4[i];
        float4 acc; acc.x = acc.y = acc.z = acc.w = 0.0f;
#pragma unroll
        for (int t = 0; t < T_STEPS; ++t) {
            const float s0 = (v.x - th[t]) > 0.0f ? 1.0f : 0.0f;
            const float s1 = (v.y - th[t]) > 0.0f ? 1.0f : 0.0f;
            const float s2 = (v.z - th[t]) > 0.0f ? 1.0f : 0.0f;
            const float s3 = (v.w - th[t]) > 0.0f ? 1.0f : 0.0f;
            v.x -= hh[t] * s0;
            v.y -= hh[t] * s1;
            v.z -= hh[t] * s2;
            v.w -= hh[t] * s3;
            acc.x += dd[t] * s0;
            acc.y += dd[t] * s1;
            acc.z += dd[t] * s2;
            acc.w += dd[t] * s3;
        }
        y4[i] = acc;
    }

    // ---- scalar tail (n_total not divisible by 4; no-op for this problem) ----
    for (int i = n4 * 4 + blockIdx.x * blockDim.x + threadIdx.x; i < n_total; i += stride) {
        float v = x_tail[i];
        float acc = 0.0f;
#pragma unroll
        for (int t = 0; t < T_STEPS; ++t) {
            const float s = (v - th[t]) > 0.0f ? 1.0f : 0.0f;
            v -= hh[t] * s;
            acc += dd[t] * s;
        }
        y_tail[i] = acc;
    }
}

extern "C" void kernel_launch(void* const* d_in, const int* in_sizes, int n_in,
                              void* d_out, int out_size, void* d_ws, size_t ws_size,
                              hipStream_t stream) {
    const float* x     = (const float*)d_in[0];
    const float* d     = (const float*)d_in[1];
    const float* h     = (const float*)d_in[2];
    const float* theta = (const float*)d_in[3];
    float* y = (float*)d_out;

    const int n  = in_sizes[0];   // B*N*1 = 16,777,216
    const int n4 = n / 4;

    const int block = 256;
    int grid = (n4 + block - 1) / block;
    if (grid > 2048) grid = 2048;   // 256 CU x 8 blocks/CU; grid-stride the rest
    if (grid < 1) grid = 1;

    fsneuron_kernel<<<grid, block, 0, stream>>>(
        (const float4*)x, d, h, theta, (float4*)y, n4, x, y, n);
}